// Round 1
// baseline (165.519 us; speedup 1.0000x reference)
//
#include <hip/hip_runtime.h>

#define DIM 8192
#define BATCH 256
#define BN 32
#define BK 32
#define BPAD 40            // padded LDS k-stride: 80B row stride = odd*16B -> conflict-free b128
#define NSTEP (DIM / BK)   // 256

typedef __attribute__((ext_vector_type(8))) short   short8;   // 8 bf16 (MFMA A/B frag)
typedef __attribute__((ext_vector_type(4))) float   f32x4;    // MFMA acc
typedef __attribute__((ext_vector_type(4))) float   floatv4;
typedef __attribute__((ext_vector_type(4))) unsigned short u16x4;

__device__ __forceinline__ unsigned short f2b(float f) {
    // round-to-nearest-even f32 -> bf16
    unsigned u = __builtin_bit_cast(unsigned, f);
    u = (u + 0x7FFFu + ((u >> 16) & 1u)) >> 16;
    return (unsigned short)u;
}

// ---- prepass: x f32 -> bf16 into workspace (4 MB) ----
__global__ __launch_bounds__(512) void cvt_x_kernel(const float* __restrict__ x,
                                                    unsigned short* __restrict__ xb) {
    int i = blockIdx.x * 512 + threadIdx.x;        // 524288 threads, 4 floats each
    floatv4 v = reinterpret_cast<const floatv4*>(x)[i];
    u16x4 o;
    o[0] = f2b(v[0]); o[1] = f2b(v[1]); o[2] = f2b(v[2]); o[3] = f2b(v[3]);
    reinterpret_cast<u16x4*>(xb)[i] = o;
}

// ---- GEMM: out[b,i] = sum_j U[i,j] * x[b,j] ----
// grid = 256 blocks (one per CU), 512 threads (8 waves).
// Block bid covers output cols n0 = bid*32 and ALL 256 rows (U read exactly once).
// Wave w owns rows [32w, 32w+32), all 32 cols: 2x2 frags of mfma_f32_16x16x32_bf16.
__global__ __launch_bounds__(512) void gemm_kernel(const unsigned short* __restrict__ xb,
                                                   const float* __restrict__ U,
                                                   float* __restrict__ out) {
    __shared__ unsigned short Blds[2][BN][BPAD];

    const int tid  = threadIdx.x;
    const int lane = tid & 63;
    const int w    = tid >> 6;
    const int n0   = blockIdx.x * BN;

    // --- B staging map: thread -> (row=tid>>4 of 32, k-pair=tid&15) : 2 f32 per thread/step
    const int srow = tid >> 4;
    const int sc   = tid & 15;
    const float* Ubase = U + (long)(n0 + srow) * DIM + 2 * sc;

    // --- A frag map: lane l -> row = 32w + (l&15) (+16 for mf=1), k = (l>>4)*8 .. +8
    const int rA = lane & 15;
    const int kf = (lane >> 4) * 8;
    const unsigned short* a0p = xb + (32 * w + rA) * DIM + kf;
    const unsigned short* a1p = a0p + 16 * DIM;

    f32x4 acc00 = {0.f, 0.f, 0.f, 0.f};
    f32x4 acc01 = acc00, acc10 = acc00, acc11 = acc00;

    // register pipelines: U 4-deep (HBM ~900cy latency), A 2-deep (L2-hot)
    float2 q[4];
    short8 aq0[2], aq1[2];

    // ---- prologue: fill pipelines, stage step 0 into LDS buf0
    q[0] = *reinterpret_cast<const float2*>(Ubase + 0 * BK);
    q[1] = *reinterpret_cast<const float2*>(Ubase + 1 * BK);
    q[2] = *reinterpret_cast<const float2*>(Ubase + 2 * BK);
    q[3] = *reinterpret_cast<const float2*>(Ubase + 3 * BK);
    aq0[0] = *reinterpret_cast<const short8*>(a0p + 0 * BK);
    aq1[0] = *reinterpret_cast<const short8*>(a1p + 0 * BK);
    aq0[1] = *reinterpret_cast<const short8*>(a0p + 1 * BK);
    aq1[1] = *reinterpret_cast<const short8*>(a1p + 1 * BK);
    {
        unsigned pk = (unsigned)f2b(q[0].x) | ((unsigned)f2b(q[0].y) << 16);
        *reinterpret_cast<unsigned*>(&Blds[0][srow][2 * sc]) = pk;
    }

    const int nl0 = lane & 15;

    for (int m = 0; m < NSTEP / 4; ++m) {
#pragma unroll
        for (int p = 0; p < 4; ++p) {
            const int kt = 4 * m + p;
            // U prefetch, distance 4 (clamped in-bounds; extra loads are dead)
            const int kpre = (kt + 4 < NSTEP) ? (kt + 4) : (NSTEP - 1);
            q[p] = *reinterpret_cast<const float2*>(Ubase + kpre * BK);

            __syncthreads();

            // B frags from LDS (double-buffered), conflict-free via BPAD
            const int buf = kt & 1;
            short8 bf0 = *reinterpret_cast<const short8*>(&Blds[buf][nl0][kf]);
            short8 bf1 = *reinterpret_cast<const short8*>(&Blds[buf][nl0 + 16][kf]);

            const short8 a0 = aq0[p & 1];
            const short8 a1 = aq1[p & 1];
            acc00 = __builtin_amdgcn_mfma_f32_16x16x32_bf16(a0, bf0, acc00, 0, 0, 0);
            acc01 = __builtin_amdgcn_mfma_f32_16x16x32_bf16(a0, bf1, acc01, 0, 0, 0);
            acc10 = __builtin_amdgcn_mfma_f32_16x16x32_bf16(a1, bf0, acc10, 0, 0, 0);
            acc11 = __builtin_amdgcn_mfma_f32_16x16x32_bf16(a1, bf1, acc11, 0, 0, 0);

            // A prefetch, distance 2 (slot reused right after its MFMA consumed it)
            const int kpa = (kt + 2 < NSTEP) ? (kt + 2) : (NSTEP - 1);
            aq0[p & 1] = *reinterpret_cast<const short8*>(a0p + kpa * BK);
            aq1[p & 1] = *reinterpret_cast<const short8*>(a1p + kpa * BK);

            // stage step kt+1 into the other LDS buffer (data loaded 3 steps ago)
            if (kt + 1 < NSTEP) {
                const float2 bn = q[(p + 1) & 3];
                unsigned pk = (unsigned)f2b(bn.x) | ((unsigned)f2b(bn.y) << 16);
                *reinterpret_cast<unsigned*>(&Blds[buf ^ 1][srow][2 * sc]) = pk;
            }
        }
    }

    // ---- epilogue: D lane mapping row=(l>>4)*4+r, col=l&15
    const int orow = 32 * w + (lane >> 4) * 4;
    const int ocol = n0 + (lane & 15);
    float* o = out + (long)orow * DIM + ocol;
#pragma unroll
    for (int r = 0; r < 4; ++r) {
        o[(long)r * DIM]             = acc00[r];
        o[(long)r * DIM + 16]        = acc01[r];
        o[(long)(r + 16) * DIM]      = acc10[r];
        o[(long)(r + 16) * DIM + 16] = acc11[r];
    }
}

extern "C" void kernel_launch(void* const* d_in, const int* in_sizes, int n_in,
                              void* d_out, int out_size, void* d_ws, size_t ws_size,
                              hipStream_t stream) {
    const float* x = (const float*)d_in[0];   // [256, 8192] f32
    const float* U = (const float*)d_in[1];   // [8192, 8192] f32
    float* outp = (float*)d_out;              // [256, 8192] f32
    unsigned short* xb = (unsigned short*)d_ws; // 4 MB bf16 copy of x

    cvt_x_kernel<<<(BATCH * DIM / 4) / 512, 512, 0, stream>>>(x, xb);
    gemm_kernel<<<DIM / BN, 512, 0, stream>>>(xb, U, outp);
}

// Round 2
// 138.899 us; speedup vs baseline: 1.1916x; 1.1916x over previous
//
#include <hip/hip_runtime.h>

#define DIM 8192
#define BATCH 256
#define BN 32
#define BK 64
#define NSTEP (DIM / BK)   // 128
#define SLD 72             // LDS k-stride (elems): 144B rows -> balanced banks for b128 frag reads

typedef __attribute__((ext_vector_type(8))) short   short8;   // 8 bf16 (MFMA A/B frag)
typedef __attribute__((ext_vector_type(4))) float   f32x4;
typedef __attribute__((ext_vector_type(4))) unsigned short u16x4;

__device__ __forceinline__ unsigned short f2b(float f) {
    unsigned u = __builtin_bit_cast(unsigned, f);
    u = (u + 0x7FFFu + ((u >> 16) & 1u)) >> 16;
    return (unsigned short)u;
}

#define WAITV(N) asm volatile("s_waitcnt vmcnt(" #N ")" ::: "memory")
#define WAITL0   asm volatile("s_waitcnt lgkmcnt(0)" ::: "memory")
#define SCHEDB   __builtin_amdgcn_sched_barrier(0)
#define BARRIER  do { asm volatile("" ::: "memory"); __builtin_amdgcn_s_barrier(); asm volatile("" ::: "memory"); } while (0)

// ---- prepass: x f32 -> bf16 into workspace (4 MB) ----
__global__ __launch_bounds__(512) void cvt_x_kernel(const float* __restrict__ x,
                                                    unsigned short* __restrict__ xb) {
    int i = blockIdx.x * 512 + threadIdx.x;
    f32x4 v = reinterpret_cast<const f32x4*>(x)[i];
    u16x4 o;
    o[0] = f2b(v[0]); o[1] = f2b(v[1]); o[2] = f2b(v[2]); o[3] = f2b(v[3]);
    reinterpret_cast<u16x4*>(xb)[i] = o;
}

// ---- GEMM: out[b,i] = sum_j U[i,j] * x[b,j] ----
// 256 blocks x 512 threads (8 waves). Block = 32 output cols x 256 batch; U read exactly once.
// Counted-vmcnt pipeline (T3/T4): raw s_barrier, never drain vmem queue in the loop.
__global__ __launch_bounds__(512, 2) void gemm_kernel(const unsigned short* __restrict__ xb,
                                                      const float* __restrict__ U,
                                                      float* __restrict__ out) {
    __shared__ unsigned short Blds[2][BN][SLD];

    const int tid  = threadIdx.x;
    const int lane = tid & 63;
    const int w    = tid >> 6;
    const int n0   = blockIdx.x * BN;

    // U staging map: thread -> (row = tid>>4 of 32, float4-quad = tid&15 of 16) : 16B/thread/step
    const int srow = tid >> 4;
    const int sq   = tid & 15;
    const f32x4* Ub = reinterpret_cast<const f32x4*>(U + (long)(n0 + srow) * DIM + 4 * sq);
    // step t -> Ub[t*16]

    // A map: lane l -> batch row = 32w + (l&15) (+16), k = (l>>4)*8 (+32*h)
    const int rA  = lane & 15;
    const int kf8 = (lane >> 4) * 8;
    const unsigned short* a0 = xb + (32 * w + rA) * DIM + kf8;
    const unsigned short* a1 = a0 + 16 * DIM;

    const int nl = lane & 15;

    f32x4 acc00 = {0.f, 0.f, 0.f, 0.f};
    f32x4 acc01 = acc00, acc10 = acc00, acc11 = acc00;

    f32x4  Uq0, Uq1;          // U queue: distance-2 (issued top of S(t) for t+2)
    short8 AqA[4], AqB[4];    // A queues: distance-2, parity slots

    // ---- prologue: issue order defines vmcnt ages: [Ut, A(0)x4, U(1), A(1)x4]
    f32x4 Ut = Ub[0];                                        // U(0)
    AqA[0] = *(const short8*)(a0 + 0 * BK);
    AqA[1] = *(const short8*)(a0 + 0 * BK + 32);
    AqA[2] = *(const short8*)(a1 + 0 * BK);
    AqA[3] = *(const short8*)(a1 + 0 * BK + 32);
    Uq1 = Ub[1 * 16];                                        // U(1)
    AqB[0] = *(const short8*)(a0 + 1 * BK);
    AqB[1] = *(const short8*)(a0 + 1 * BK + 32);
    AqB[2] = *(const short8*)(a1 + 1 * BK);
    AqB[3] = *(const short8*)(a1 + 1 * BK + 32);
    WAITV(9);                                                // U(0) arrived
    {
        u16x4 o; o[0] = f2b(Ut[0]); o[1] = f2b(Ut[1]); o[2] = f2b(Ut[2]); o[3] = f2b(Ut[3]);
        *reinterpret_cast<u16x4*>(&Blds[0][srow][4 * sq]) = o;
    }
    WAITL0;
    BARRIER;

    // Steady state at entry of S(t): in flight [A(t)x4, U(t+1), A(t+1)x4] = 9.
    // S(t): issue U(t+2) (10) -> WAITV(6): A(t) done -> MFMA -> WAITV(5): U(t+1) done
    //       -> cvt+ds_write buf^1 -> issue A(t+2)x4 (9) -> lgkmcnt(0) -> raw barrier.
#define STEP(T, UQISS, UQRDY, AQ, BUFR)                                              \
    do {                                                                             \
        short8 b0_0 = *(const short8*)&Blds[BUFR][nl     ][kf8     ];                \
        short8 b1_0 = *(const short8*)&Blds[BUFR][nl + 16][kf8     ];                \
        short8 b0_1 = *(const short8*)&Blds[BUFR][nl     ][kf8 + 32];                \
        short8 b1_1 = *(const short8*)&Blds[BUFR][nl + 16][kf8 + 32];                \
        { int tp = ((T) + 2 < NSTEP) ? (T) + 2 : NSTEP - 1; UQISS = Ub[tp * 16]; }   \
        WAITV(6); SCHEDB;                                                            \
        WAITL0; SCHEDB;                                                              \
        __builtin_amdgcn_s_setprio(1);                                               \
        acc00 = __builtin_amdgcn_mfma_f32_16x16x32_bf16(AQ[0], b0_0, acc00, 0, 0, 0);\
        acc01 = __builtin_amdgcn_mfma_f32_16x16x32_bf16(AQ[0], b1_0, acc01, 0, 0, 0);\
        acc10 = __builtin_amdgcn_mfma_f32_16x16x32_bf16(AQ[2], b0_0, acc10, 0, 0, 0);\
        acc11 = __builtin_amdgcn_mfma_f32_16x16x32_bf16(AQ[2], b1_0, acc11, 0, 0, 0);\
        acc00 = __builtin_amdgcn_mfma_f32_16x16x32_bf16(AQ[1], b0_1, acc00, 0, 0, 0);\
        acc01 = __builtin_amdgcn_mfma_f32_16x16x32_bf16(AQ[1], b1_1, acc01, 0, 0, 0);\
        acc10 = __builtin_amdgcn_mfma_f32_16x16x32_bf16(AQ[3], b0_1, acc10, 0, 0, 0);\
        acc11 = __builtin_amdgcn_mfma_f32_16x16x32_bf16(AQ[3], b1_1, acc11, 0, 0, 0);\
        __builtin_amdgcn_s_setprio(0);                                               \
        WAITV(5); SCHEDB;                                                            \
        {                                                                            \
            u16x4 o; o[0] = f2b(UQRDY[0]); o[1] = f2b(UQRDY[1]);                     \
            o[2] = f2b(UQRDY[2]); o[3] = f2b(UQRDY[3]);                              \
            *reinterpret_cast<u16x4*>(&Blds[(BUFR) ^ 1][srow][4 * sq]) = o;          \
        }                                                                            \
        { int ta = ((T) + 2 < NSTEP) ? (T) + 2 : NSTEP - 1;                          \
          AQ[0] = *(const short8*)(a0 + ta * BK);                                    \
          AQ[1] = *(const short8*)(a0 + ta * BK + 32);                               \
          AQ[2] = *(const short8*)(a1 + ta * BK);                                    \
          AQ[3] = *(const short8*)(a1 + ta * BK + 32); }                             \
        WAITL0;                                                                      \
        BARRIER;                                                                     \
    } while (0)

    for (int t = 0; t < NSTEP; t += 2) {
        STEP(t,     Uq0, Uq1, AqA, 0);   // even: read buf0, write buf1
        STEP(t + 1, Uq1, Uq0, AqB, 1);   // odd:  read buf1, write buf0
    }
#undef STEP

    // ---- epilogue: D mapping row=(l>>4)*4+r, col=l&15 (verified)
    const int orow = 32 * w + (lane >> 4) * 4;
    const int ocol = n0 + (lane & 15);
    float* o = out + (long)orow * DIM + ocol;
#pragma unroll
    for (int r = 0; r < 4; ++r) {
        o[(long)r * DIM]             = acc00[r];
        o[(long)r * DIM + 16]        = acc01[r];
        o[(long)(r + 16) * DIM]      = acc10[r];
        o[(long)(r + 16) * DIM + 16] = acc11[r];
    }
}

extern "C" void kernel_launch(void* const* d_in, const int* in_sizes, int n_in,
                              void* d_out, int out_size, void* d_ws, size_t ws_size,
                              hipStream_t stream) {
    const float* x = (const float*)d_in[0];     // [256, 8192] f32
    const float* U = (const float*)d_in[1];     // [8192, 8192] f32
    float* outp = (float*)d_out;                // [256, 8192] f32
    unsigned short* xb = (unsigned short*)d_ws; // 4 MB bf16 copy of x

    cvt_x_kernel<<<(BATCH * DIM / 4) / 512, 512, 0, stream>>>(x, xb);
    gemm_kernel<<<DIM / BN, 512, 0, stream>>>(xb, U, outp);
}